// Round 16
// baseline (704.056 us; speedup 1.0000x reference)
//
#include <hip/hip_runtime.h>
#include <hip/hip_bf16.h>
#include <math.h>

#define NN 8192
#define FI 128
#define FO 64
#define ALPHA 0.2f

__device__ __forceinline__ float lk(float e)   { return fmaxf(e, ALPHA * e); }
__device__ __forceinline__ float elu1(float v) { return v > 0.f ? v : expm1f(v); }

// ---- 1. h = x@W, s1 = h.a1, s2 = h.a2 (proven skeleton) ----------------------
__global__ __launch_bounds__(256) void k_prep(
    const float* __restrict__ x, const float* __restrict__ W,
    const float* __restrict__ a,
    float* __restrict__ h_out, float* __restrict__ s1, float* __restrict__ s2)
{
    __shared__ float Wl[FI * FO];
    __shared__ float xrow[4][FI];
    const int tid = threadIdx.x;
    for (int i = tid * 4; i < FI * FO; i += 1024)
        *(float4*)&Wl[i] = *(const float4*)&W[i];
    const int wave = tid >> 6, lane = tid & 63;
    const int row  = blockIdx.x * 4 + wave;
    *(float2*)&xrow[wave][lane * 2] = *(const float2*)&x[(size_t)row * FI + lane * 2];
    __syncthreads();
    float h = 0.f;
    #pragma unroll 8
    for (int k = 0; k < FI; ++k)
        h = fmaf(xrow[wave][k], Wl[k * FO + lane], h);
    h_out[(size_t)row * FO + lane] = h;
    float p1 = h * a[lane], p2 = h * a[FO + lane];
    #pragma unroll
    for (int off = 32; off >= 1; off >>= 1) {
        p1 += __shfl_xor(p1, off, 64);
        p2 += __shfl_xor(p2, off, 64);
    }
    if (lane == 0) { s1[row] = p1; s2[row] = p2; }
}

// ---- 2. one block per row: reference softmax algorithm, FP32 OUTPUT ----------
__global__ __launch_bounds__(256) void k_row(
    const float* __restrict__ h, const float* __restrict__ s1v,
    const float* __restrict__ s2v, const int* __restrict__ adj,
    float* __restrict__ out)
{
    __shared__ float wl[NN];        // 32 KB: this row's weights
    __shared__ float red[256];
    __shared__ float redc[4][FO];
    __shared__ float zs, ms;
    const int i   = blockIdx.x;
    const int tid = threadIdx.x;
    const float s1i = s1v[i];
    const size_t arow = (size_t)i * NN;

    // pass A: true masked row max (exactly what np softmax computes)
    float mx = -INFINITY;
    for (int j = tid; j < NN; j += 256) {
        if (adj[arow + j] > 0) {
            const float e = s1i + s2v[j];
            mx = fmaxf(mx, lk(e));
        }
    }
    red[tid] = mx; __syncthreads();
    for (int s = 128; s > 0; s >>= 1) {
        if (tid < s) red[tid] = fmaxf(red[tid], red[tid + s]);
        __syncthreads();
    }
    if (tid == 0) ms = red[0];
    __syncthreads();
    const float m = ms;
    const bool nomask = !isfinite(m);   // all-masked row -> uniform softmax

    // pass B: weights + denominator
    float zp = 0.f;
    for (int j = tid; j < NN; j += 256) {
        float w;
        if (nomask) w = 1.f;
        else if (adj[arow + j] > 0) w = __expf(lk(s1i + s2v[j]) - m);
        else w = 0.f;
        wl[j] = w; zp += w;
    }
    red[tid] = zp; __syncthreads();
    for (int s = 128; s > 0; s >>= 1) {
        if (tid < s) red[tid] += red[tid + s];
        __syncthreads();
    }
    if (tid == 0) zs = red[0];
    __syncthreads();
    const float z = zs;

    // pass C: h'[i][c] = sum_j w[j] * h[j][c]  (wave g owns a contiguous j-range)
    const int g = tid >> 6, c = tid & 63;
    float acc = 0.f;
    const int j0 = g * (NN / 4), j1 = j0 + NN / 4;
    for (int j = j0; j < j1; ++j)
        acc = fmaf(wl[j], h[(size_t)j * FO + c], acc);
    redc[g][c] = acc; __syncthreads();

    if (tid < FO) {
        const float hp = (redc[0][tid] + redc[1][tid] + redc[2][tid] + redc[3][tid]) / z;
        out[(size_t)i * FO + tid] = elu1(hp);   // FP32 store — the fix
    }
}

extern "C" void kernel_launch(void* const* d_in, const int* in_sizes, int n_in,
                              void* d_out, int out_size, void* d_ws, size_t ws_size,
                              hipStream_t stream)
{
    const float* x = nullptr; const int* adj = nullptr;
    const float* W = nullptr; const float* a = nullptr;
    for (int i = 0; i < n_in; ++i) {
        const long long s = in_sizes[i];
        if      (s == (long long)NN * FI) x   = (const float*)d_in[i];
        else if (s == (long long)NN * NN) adj = (const int*)d_in[i];
        else if (s == (long long)FI * FO) W   = (const float*)d_in[i];
        else if (s == (long long)2 * FO)  a   = (const float*)d_in[i];
    }
    if (!x)   x   = (const float*)d_in[0];
    if (!adj) adj = (const int*)d_in[1];
    if (!W)   W   = (const float*)d_in[2];
    if (!a)   a   = (const float*)d_in[3];
    float* out = (float*)d_out;   // reference output dtype is float32

    char* ws = (char*)d_ws;
    float* h  = (float*)(ws);                 // 2 MB
    float* s1 = (float*)(ws + (2u << 20));    // 32 KB
    float* s2 = (float*)(ws + (2u << 20) + 32768);

    k_prep<<<NN / 4, 256, 0, stream>>>(x, W, a, h, s1, s2);
    k_row <<<NN, 256, 0, stream>>>(h, s1, s2, adj, out);
}

// Round 17
// 126.431 us; speedup vs baseline: 5.5687x; 5.5687x over previous
//
#include <hip/hip_runtime.h>
#include <hip/hip_bf16.h>
#include <math.h>

#define NN 8192
#define FI 128
#define FO 64
#define ALPHA 0.2f
#define KCHUNK 2048            // j-strip per wave (4 waves cover 8192)

typedef __attribute__((ext_vector_type(8))) short bf16x8;
typedef __attribute__((ext_vector_type(4))) float f32x4;
typedef unsigned int uint;
typedef unsigned short ushort;

__device__ __forceinline__ float lk(float e)   { return fmaxf(e, ALPHA * e); }
__device__ __forceinline__ float elu1(float v) { return v > 0.f ? v : expm1f(v); }
__device__ __forceinline__ float bf2f(ushort u) {
    union { uint u; float f; } x; x.u = ((uint)u) << 16; return x.f;
}
__device__ __forceinline__ short f2bf(float f) {   // RNE
    union { float f; uint u; } x; x.f = f;
    uint r = x.u + 0x7fffu + ((x.u >> 16) & 1u);
    return (short)(r >> 16);
}

// ---- 1. h = x@W (reg), hT bf16 [FO][NN], s1 = h.a1, s2 = h.a2 -----------------
__global__ __launch_bounds__(256) void k_prep(
    const float* __restrict__ x, const float* __restrict__ W,
    const float* __restrict__ a,
    __hip_bfloat16* __restrict__ hT, float* __restrict__ s1, float* __restrict__ s2)
{
    __shared__ float Wl[FI * FO];
    __shared__ float xrow[4][FI];
    const int tid = threadIdx.x;
    for (int i = tid * 4; i < FI * FO; i += 1024)
        *(float4*)&Wl[i] = *(const float4*)&W[i];
    const int wave = tid >> 6, lane = tid & 63;
    const int row  = blockIdx.x * 4 + wave;
    *(float2*)&xrow[wave][lane * 2] = *(const float2*)&x[(size_t)row * FI + lane * 2];
    __syncthreads();
    float h = 0.f;
    #pragma unroll 8
    for (int k = 0; k < FI; ++k)
        h = fmaf(xrow[wave][k], Wl[k * FO + lane], h);
    hT[(size_t)lane * NN + row] = __float2bfloat16(h);
    float p1 = h * a[lane], p2 = h * a[FO + lane];
    #pragma unroll
    for (int off = 32; off >= 1; off >>= 1) {
        p1 += __shfl_xor(p1, off, 64);
        p2 += __shfl_xor(p2, off, 64);
    }
    if (lane == 0) { s1[row] = p1; s2[row] = p2; }
}

// ---- 2. global max of s2 -------------------------------------------------------
__global__ __launch_bounds__(256) void k_s2max(
    const float* __restrict__ s2, float* __restrict__ s2max)
{
    __shared__ float red[256];
    float m = -1e30f;
    for (int i = threadIdx.x; i < NN; i += 256) m = fmaxf(m, s2[i]);
    red[threadIdx.x] = m;
    __syncthreads();
    for (int s = 128; s > 0; s >>= 1) {
        if (threadIdx.x < s) red[threadIdx.x] = fmaxf(red[threadIdx.x], red[threadIdx.x + s]);
        __syncthreads();
    }
    if (threadIdx.x == 0) *s2max = red[0];
}

// ---- 3. fused masked-softmax @ h via MFMA; fp32 out ---------------------------
// 512 blocks x 256 threads (4 waves). Block = 16 rows; wave ks = j-strip of 2048.
__global__ __launch_bounds__(256) void k_attn(
    const int* __restrict__ adj, const float* __restrict__ s1v,
    const float* __restrict__ s2v, const float* __restrict__ s2maxp,
    const __hip_bfloat16* __restrict__ hT, float* __restrict__ out)
{
    __shared__ float red[3][64][16];   // 12 KB: strips 1..3 accumulators
    __shared__ float zp[4][16];
    const int tid  = threadIdx.x;
    const int ks   = tid >> 6;          // wave = K-strip 0..3
    const int lane = tid & 63;
    const int r16  = lane & 15;         // A-fragment row
    const int g    = lane >> 4;         // A-fragment k-group
    const int rowbase = blockIdx.x * 16;
    const int row  = rowbase + r16;

    const float s1 = s1v[row];
    const float mv = s1 + s2maxp[0];
    const float m  = fmaxf(mv, ALPHA * mv);   // >= every leaky(e) in these rows

    f32x4 acc0 = {0,0,0,0}, acc1 = {0,0,0,0}, acc2 = {0,0,0,0}, acc3 = {0,0,0,0};
    float z = 0.f;
    const size_t adjrow = (size_t)row * NN;
    const int j0base = ks * KCHUNK;

    for (int k0 = 0; k0 < KCHUNK; k0 += 32) {
        const int j0 = j0base + k0 + g * 8;
        const int4   adja = *(const int4*)(adj + adjrow + j0);
        const int4   adjb = *(const int4*)(adj + adjrow + j0 + 4);
        const float4 s2a  = *(const float4*)(s2v + j0);
        const float4 s2b  = *(const float4*)(s2v + j0 + 4);
        // B fragments: lane holds B[k=g*8+e][n=r16+16t] = h[j0+e][n] = hT[n][j0+e]
        const bf16x8 b0 = *(const bf16x8*)(hT + (size_t)(r16)      * NN + j0);
        const bf16x8 b1 = *(const bf16x8*)(hT + (size_t)(16 + r16) * NN + j0);
        const bf16x8 b2 = *(const bf16x8*)(hT + (size_t)(32 + r16) * NN + j0);
        const bf16x8 b3 = *(const bf16x8*)(hT + (size_t)(48 + r16) * NN + j0);

        const int   av8[8] = {adja.x, adja.y, adja.z, adja.w, adjb.x, adjb.y, adjb.z, adjb.w};
        const float s2e[8] = {s2a.x, s2a.y, s2a.z, s2a.w, s2b.x, s2b.y, s2b.z, s2b.w};
        bf16x8 af;
        #pragma unroll
        for (int e = 0; e < 8; ++e) {
            const float v  = s1 + s2e[e];
            const float w  = __expf(lk(v) - m);
            const float wm = (av8[e] > 0) ? w : 0.f;
            const short wb = f2bf(wm);
            af[e] = wb;
            z += bf2f((ushort)wb);    // denominator from the SAME rounded weights
        }
        acc0 = __builtin_amdgcn_mfma_f32_16x16x32_bf16(af, b0, acc0, 0, 0, 0);
        acc1 = __builtin_amdgcn_mfma_f32_16x16x32_bf16(af, b1, acc1, 0, 0, 0);
        acc2 = __builtin_amdgcn_mfma_f32_16x16x32_bf16(af, b2, acc2, 0, 0, 0);
        acc3 = __builtin_amdgcn_mfma_f32_16x16x32_bf16(af, b3, acc3, 0, 0, 0);
    }

    // per-row z within wave: sum the 4 k-groups holding the same row
    z += __shfl_xor(z, 16, 64);
    z += __shfl_xor(z, 32, 64);

    if (ks > 0) {
        float* dst = &red[ks - 1][lane][0];
        #pragma unroll
        for (int r = 0; r < 4; ++r) {
            dst[r]      = acc0[r];
            dst[4 + r]  = acc1[r];
            dst[8 + r]  = acc2[r];
            dst[12 + r] = acc3[r];
        }
    }
    if (lane < 16) zp[ks][lane] = z;
    __syncthreads();

    if (ks == 0) {
        #pragma unroll
        for (int w = 0; w < 3; ++w) {
            const float* src = &red[w][lane][0];
            #pragma unroll
            for (int r = 0; r < 4; ++r) {
                acc0[r] += src[r];
                acc1[r] += src[4 + r];
                acc2[r] += src[8 + r];
                acc3[r] += src[12 + r];
            }
        }
        #pragma unroll
        for (int r = 0; r < 4; ++r) {
            const int rr = g * 4 + r;           // C/D layout: row=(lane>>4)*4+reg
            float zt = zp[0][rr] + zp[1][rr] + zp[2][rr] + zp[3][rr];
            if (zt == 0.f) zt = 1.f;            // unreachable for this data
            const size_t o = (size_t)(rowbase + rr) * FO + r16;
            out[o]      = elu1(acc0[r] / zt);
            out[o + 16] = elu1(acc1[r] / zt);
            out[o + 32] = elu1(acc2[r] / zt);
            out[o + 48] = elu1(acc3[r] / zt);
        }
    }
}

extern "C" void kernel_launch(void* const* d_in, const int* in_sizes, int n_in,
                              void* d_out, int out_size, void* d_ws, size_t ws_size,
                              hipStream_t stream)
{
    const float* x = nullptr; const int* adj = nullptr;
    const float* W = nullptr; const float* a = nullptr;
    for (int i = 0; i < n_in; ++i) {
        const long long s = in_sizes[i];
        if      (s == (long long)NN * FI) x   = (const float*)d_in[i];
        else if (s == (long long)NN * NN) adj = (const int*)d_in[i];
        else if (s == (long long)FI * FO) W   = (const float*)d_in[i];
        else if (s == (long long)2 * FO)  a   = (const float*)d_in[i];
    }
    if (!x)   x   = (const float*)d_in[0];
    if (!adj) adj = (const int*)d_in[1];
    if (!W)   W   = (const float*)d_in[2];
    if (!a)   a   = (const float*)d_in[3];
    float* out = (float*)d_out;

    char* ws = (char*)d_ws;
    float*          s1    = (float*)(ws);                    // 32 KB
    float*          s2    = (float*)(ws + 32768);            // 32 KB
    float*          s2max = (float*)(ws + 65536);            // 4 B
    __hip_bfloat16* hT    = (__hip_bfloat16*)(ws + 131072);  // 1 MB

    k_prep <<<NN / 4, 256, 0, stream>>>(x, W, a, hT, s1, s2);
    k_s2max<<<1, 256, 0, stream>>>(s2, s2max);
    k_attn <<<NN / 16, 256, 0, stream>>>(adj, s1, s2, s2max, hT, out);
}